// Round 4
// baseline (9992.516 us; speedup 1.0000x reference)
//
#include <hip/hip_runtime.h>
#include <stdint.h>

#define B_  32
#define S_  32
#define V_  100
#define HD_ 32
#define HID_ 64
#define ND_ 10
#define NROW (B_*V_)

// ---- workspace float offsets ----
#define WO_LDS   0            // 40 chunks x 256 floats (f1:0-7, g1:8-15, fg3:16-31, e1:32-39)
#define WO_FW1E  10240        // 2 x 64  (fW1 rows 32(dft),33(last))
#define WO_GW1E  10368        // 64      (gW1 row 32(dft))
#define WO_FW2T  10432        // 64x64 [o][k]  (w2f -> VGPRs)
#define WO_GW2C  14528        // 64x64 chunk-major [c][o][4] (w2g -> LDS)
#define WO_HA    18624
#define WO_HB    (WO_HA + NROW*HD_)
#define WO_ACC   (WO_HB + NROW*HD_)
#define WO_PREVL (WO_ACC + NROW)
#define WO_PREVT (WO_PREVL + NROW)
#define WO_LTLOG (WO_PREVT + NROW)

// ---------------- threefry2x32 (JAX-compatible) ----------------
__host__ __device__ inline void tf2x32(uint32_t k0, uint32_t k1,
                                       uint32_t& x0, uint32_t& x1) {
  uint32_t ks0 = k0, ks1 = k1, ks2 = k0 ^ k1 ^ 0x1BD11BDAu;
#define TFR(r) { x0 += x1; x1 = (x1 << (r)) | (x1 >> (32 - (r))); x1 ^= x0; }
  x0 += ks0; x1 += ks1;
  TFR(13) TFR(15) TFR(26) TFR(6)
  x0 += ks1; x1 += ks2 + 1u;
  TFR(17) TFR(29) TFR(16) TFR(24)
  x0 += ks2; x1 += ks0 + 2u;
  TFR(13) TFR(15) TFR(26) TFR(6)
  x0 += ks0; x1 += ks1 + 3u;
  TFR(17) TFR(29) TFR(16) TFR(24)
  x0 += ks1; x1 += ks2 + 4u;
  TFR(13) TFR(15) TFR(26) TFR(6)
  x0 += ks2; x1 += ks0 + 5u;
#undef TFR
}

// ---------------- erfinv (XLA / Giles f32 polynomial) — keep precise ----------------
__device__ __forceinline__ float erfinv_f(float x) {
  float w = -log1pf(-x * x);
  float p;
  if (w < 5.0f) {
    w -= 2.5f;
    p = 2.81022636e-08f;
    p = fmaf(p, w, 3.43273939e-07f);
    p = fmaf(p, w, -3.5233877e-06f);
    p = fmaf(p, w, -4.39150654e-06f);
    p = fmaf(p, w, 0.00021858087f);
    p = fmaf(p, w, -0.00125372503f);
    p = fmaf(p, w, -0.00417768164f);
    p = fmaf(p, w, 0.246640727f);
    p = fmaf(p, w, 1.50140941f);
  } else {
    w = sqrtf(w) - 3.0f;
    p = -0.000200214257f;
    p = fmaf(p, w, 0.000100950558f);
    p = fmaf(p, w, 0.00134934322f);
    p = fmaf(p, w, -0.00367342844f);
    p = fmaf(p, w, 0.00573950773f);
    p = fmaf(p, w, -0.0076224613f);
    p = fmaf(p, w, 0.00943887047f);
    p = fmaf(p, w, 1.00167406f);
    p = fmaf(p, w, 2.83297682f);
  }
  return p * x;
}

// ---------------- fast device math ----------------
__device__ __forceinline__ float tanhf_fast(float x) {
  float ax = fabsf(x);
  float e  = __expf(-2.0f * ax);
  float r  = (1.0f - e) * __builtin_amdgcn_rcpf(1.0f + e);
  return copysignf(r, x);
}
__device__ __forceinline__ float softplus_fast(float x) {
  return fmaxf(x, 0.0f) + __logf(1.0f + __expf(-fabsf(x)));
}
__device__ __forceinline__ float rl(float v, int k) {
  return __uint_as_float(__builtin_amdgcn_readlane(__float_as_uint(v), (uint32_t)k));
}

// used by msg_k only
template<int K4, int O>
__device__ __forceinline__ float dotWxT(const float* __restrict__ W,
                                        const float* __restrict__ x,
                                        float a, int lane) {
#pragma unroll
  for (int kb = 0; kb < K4; ++kb) {
    float4 xv = *(const float4*)(x + kb * 4);
    a = fmaf(xv.x, W[(kb * 4 + 0) * O + lane], a);
    a = fmaf(xv.y, W[(kb * 4 + 1) * O + lane], a);
    a = fmaf(xv.z, W[(kb * 4 + 2) * O + lane], a);
    a = fmaf(xv.w, W[(kb * 4 + 3) * O + lane], a);
  }
  return a;
}

struct SubK { uint32_t k[ND_][2]; };

// ---------------- prep: transpose weights into ws ----------------
__global__ void prep_k(const float* __restrict__ fW1, const float* __restrict__ gW1,
                       const float* __restrict__ fW3, const float* __restrict__ gW3,
                       const float* __restrict__ eW1, const float* __restrict__ fW2,
                       const float* __restrict__ gW2, float* __restrict__ ws) {
  int i = blockIdx.x * 256 + threadIdx.x;
  if (i < 10240) {
    int c = i >> 8, r = i & 255, o = r >> 2, ii = r & 3;
    float v;
    if (c < 8)       v = fW1[(c * 4 + ii) * HID_ + o];
    else if (c < 16) v = gW1[((c - 8) * 4 + ii) * HID_ + o];
    else if (c < 32) { int k = (c - 16) * 4 + ii;
                       v = (o < 32) ? fW3[k * HD_ + o] : gW3[k * HD_ + (o - 32)]; }
    else             v = eW1[((c - 32) * 4 + ii) * HID_ + o];
    ws[WO_LDS + i] = v;
  } else if (i < 10368) { int j = i - 10240; ws[i] = fW1[(32 + (j >> 6)) * HID_ + (j & 63)]; }
  else if (i < 10432)   { ws[i] = gW1[32 * HID_ + (i - 10368)]; }
  else if (i < 14528)   { int j = i - 10432; ws[i] = fW2[(j & 63) * HID_ + (j >> 6)]; }
  else if (i < 18624)   { int j = i - 14528; int c = j >> 8, o = (j >> 2) & 63, ii = j & 3;
                          ws[i] = gW2[(4 * c + ii) * HID_ + o]; }
}

// ---------------- Euler kernel: one interval, 1 row/wave ----------------
__launch_bounds__(256, 3)
__global__ void euler_k(const float* __restrict__ time_, const int* __restrict__ type_,
                        const float* __restrict__ mask_, const float* __restrict__ ws,
                        const float* __restrict__ fb1, const float* __restrict__ fb2,
                        const float* __restrict__ fb3, const float* __restrict__ gb1,
                        const float* __restrict__ gb2, const float* __restrict__ gb3,
                        const float* __restrict__ eb1, const float* __restrict__ eW2,
                        const float* __restrict__ eb2,
                        float* __restrict__ h, float* __restrict__ acc,
                        float* __restrict__ prevl, float* __restrict__ prevt,
                        float* __restrict__ ltlog, float* __restrict__ dout,
                        int s, SubK sk) {
  __shared__ float ldsL1[4096];   // f1 chunks 0-7, g1 chunks 8-15
  __shared__ float ldsG2[4096];   // gW2 chunk-major
  __shared__ float xb[4][128];    // per-wave x buffer (xf | xg)
  const int w = threadIdx.x >> 6, lane = threadIdx.x & 63;
  const int row = blockIdx.x * 4 + w;
  const int b = row / V_, v = row - b * V_;
  const bool lo = (lane < 32);

  { // stage L1 + gW2 weights to LDS
    const float4* s1 = (const float4*)(ws + WO_LDS);
    const float4* s2 = (const float4*)(ws + WO_GW2C);
    float4* d1 = (float4*)ldsL1;
    float4* d2 = (float4*)ldsG2;
    for (int t = threadIdx.x; t < 1024; t += 256) { d1[t] = s1[t]; d2[t] = s2[t]; }
  }

  // fW2 columns in registers (64 VGPRs)
  float w2f[64];
  {
    const float* f2 = ws + WO_FW2T + lane * 64;
#pragma unroll
    for (int c = 0; c < 16; ++c) {
      float4 a = *(const float4*)(f2 + c * 4);
      w2f[4*c+0]=a.x; w2f[4*c+1]=a.y; w2f[4*c+2]=a.z; w2f[4*c+3]=a.w;
    }
  }

  const float* __restrict__ w3glb = ws + WO_LDS + 16 * 256;  // fg3 chunks (global, L1$)
  const float* __restrict__ eWglb = ws + WO_LDS + 32 * 256;  // e1 chunks  (global, L1$)

  const float fb1r = fb1[lane], fb2r = fb2[lane];
  const float gb1r = gb1[lane], gb2r = gb2[lane];
  const float eb1r = eb1[lane], eW2r = eW2[lane], eb2r = eb2[0];
  const float b3r  = lo ? fb3[lane] : gb3[lane - 32];
  const float fe0 = ws[WO_FW1E + lane], fe1 = ws[WO_FW1E + 64 + lane];
  const float ge0 = ws[WO_GW1E + lane];

  const float t0 = time_[b * S_ + s - 1];
  const float t1 = time_[b * S_ + s];
  const float dt = (t1 - t0) / 10.0f;
  const float sq = sqrtf(dt);
  const float msk  = mask_[b * S_ + s];
  const float mskp = mask_[b * S_ + s - 1];
  float hreg = h[row * HD_ + (lane & 31)];   // both halves mirror h

  __syncthreads();

  auto eint = [&]() -> float {
    float a0 = eb1r, a1 = 0.0f;
#pragma unroll
    for (int c = 0; c < 8; ++c) {
      const float4 we = *(const float4*)(eWglb + c * 256 + lane * 4);
      a0 = fmaf(rl(hreg, 4*c+0), we.x, a0);
      a1 = fmaf(rl(hreg, 4*c+1), we.y, a1);
      a0 = fmaf(rl(hreg, 4*c+2), we.z, a0);
      a1 = fmaf(rl(hreg, 4*c+3), we.w, a1);
    }
    float t = tanhf_fast(a0 + a1) * eW2r;
#pragma unroll
    for (int o = 1; o < 64; o <<= 1) t += __shfl_xor(t, o, 64);
    return softplus_fast(t + eb2r);
  };

  float lprev = eint();
  float accl = acc[row];
  if (s > 1) accl += (prevl[row] * mskp + lprev * msk) * (t0 - prevt[row]) * msk;

#pragma unroll 1
  for (int j = 0; j < ND_; ++j) {
    const float dft = dt * (float)(j + 1);
    // ---- layer 1 (f & g), W from LDS, x = hreg via readlane ----
    float af0 = fb1r, af1 = 0.0f, ag0 = gb1r, ag1 = 0.0f;
#pragma unroll
    for (int c = 0; c < 8; ++c) {
      const float4 wf = *(const float4*)&ldsL1[(c * 64 + lane) * 4];
      const float4 wg = *(const float4*)&ldsL1[((8 + c) * 64 + lane) * 4];
      float s0 = rl(hreg, 4*c+0), s1 = rl(hreg, 4*c+1);
      float s2 = rl(hreg, 4*c+2), s3 = rl(hreg, 4*c+3);
      af0 = fmaf(s0, wf.x, af0); ag0 = fmaf(s0, wg.x, ag0);
      af1 = fmaf(s1, wf.y, af1); ag1 = fmaf(s1, wg.y, ag1);
      af0 = fmaf(s2, wf.z, af0); ag0 = fmaf(s2, wg.z, ag0);
      af1 = fmaf(s3, wf.w, af1); ag1 = fmaf(s3, wg.w, ag1);
    }
    af0 = fmaf(dft, fe0, af0); af1 = fmaf(t0, fe1, af1);
    ag0 = fmaf(dft, ge0, ag0);
    float xf = tanhf_fast(af0 + af1), xg = tanhf_fast(ag0 + ag1);
    // publish x for layer 3
    xb[w][lane] = xf; xb[w][64 + lane] = xg;
    // ---- layer 2: f weights in VGPR, g weights from LDS; x via readlane ----
    float bf0 = fb2r, bf1 = 0.0f, bg0 = gb2r, bg1 = 0.0f;
#pragma unroll
    for (int c = 0; c < 16; ++c) {
      const float4 wg = *(const float4*)&ldsG2[(c * 64 + lane) * 4];
      float s0 = rl(xf, 4*c+0), s1 = rl(xf, 4*c+1);
      float s2 = rl(xf, 4*c+2), s3 = rl(xf, 4*c+3);
      float u0 = rl(xg, 4*c+0), u1 = rl(xg, 4*c+1);
      float u2 = rl(xg, 4*c+2), u3 = rl(xg, 4*c+3);
      bf0 = fmaf(s0, w2f[4*c+0], bf0); bg0 = fmaf(u0, wg.x, bg0);
      bf1 = fmaf(s1, w2f[4*c+1], bf1); bg1 = fmaf(u1, wg.y, bg1);
      bf0 = fmaf(s2, w2f[4*c+2], bf0); bg0 = fmaf(u2, wg.z, bg0);
      bf1 = fmaf(s3, w2f[4*c+3], bf1); bg1 = fmaf(u3, wg.w, bg1);
    }
    float yf = tanhf_fast(bf0 + bf1), yg = tanhf_fast(bg0 + bg1);
    xb[w][lane] = yf; xb[w][64 + lane] = yg;   // overwrite with layer-2 activations
    // ---- layer 3: lanes<32 -> f3 (x=yf), lanes>=32 -> g3 (x=yg) ----
    float a30 = b3r, a31 = 0.0f;
    const float* xsrc = &xb[w][lo ? 0 : 64];
#pragma unroll
    for (int c = 0; c < 16; ++c) {
      const float4 wc = *(const float4*)(w3glb + c * 256 + lane * 4);
      const float4 xv = *(const float4*)(xsrc + c * 4);
      a30 = fmaf(xv.x, wc.x, a30); a31 = fmaf(xv.y, wc.y, a31);
      a30 = fmaf(xv.z, wc.z, a30); a31 = fmaf(xv.w, wc.w, a31);
    }
    float a3 = a30 + a31;
    // ---- exchange drift/diff across halves; both halves update h ----
    float part  = __shfl_xor(a3, 32, 64);
    float drift = lo ? a3 : part;
    float diff  = lo ? part : a3;
    const int i = lane & 31;
    uint32_t x0 = 0u, x1 = (uint32_t)(row * HD_ + i);
    tf2x32(sk.k[j][0], sk.k[j][1], x0, x1);
    uint32_t bits = x0 ^ x1;
    float fr = __uint_as_float(0x3f800000u | (bits >> 9)) - 1.0f;
    const float LOW = -0.99999994f;
    float u = fmaxf(LOW, fr * 2.0f + LOW);
    float n = 1.4142135f * erfinv_f(u);
    hreg = hreg + drift * dt + (diff * sq) * n;
    // ---- intensity + trapezoid ----
    float l = eint();
    float tj  = t0 + dt * (float)j;
    float tj1 = t0 + dt * (float)(j + 1);
    accl += (lprev * msk + l * msk) * ((tj1 - tj) * msk);
    lprev = l;
  }

  if (lo) h[row * HD_ + lane] = hreg;
  if (lane == 0) {
    acc[row] = accl;
    prevl[row] = lprev;
    prevt[row] = t0 + dt * 10.0f;
    dout[1 + (b * S_ + s) * V_ + v] = lprev;
    int ev = type_[b * S_ + s];
    if (v == ev) ltlog[s * B_ + b] = logf(lprev + 1e-16f) * msk;
  }
}

// ---------------- msg_jump kernel ----------------
__launch_bounds__(256)
__global__ void msg_k(const int* __restrict__ type_, const float* __restrict__ mask_,
                      const float* __restrict__ logits, const float* __restrict__ h0,
                      const float* __restrict__ mW1, const float* __restrict__ mb1,
                      const float* __restrict__ mW2, const float* __restrict__ mb2,
                      const float* __restrict__ jW1, const float* __restrict__ jb1,
                      const float* __restrict__ jW2, const float* __restrict__ jb2,
                      const float* __restrict__ eW1, const float* __restrict__ eb1,
                      const float* __restrict__ eW2, const float* __restrict__ eb2,
                      const float* __restrict__ hsrc, float* __restrict__ hdst,
                      float* __restrict__ acc, float* __restrict__ ltlog,
                      float* __restrict__ dout, int s) {
  __shared__ float xls[4][64];
  __shared__ float als[4][64];
  const int w = threadIdx.x >> 6, lane = threadIdx.x & 63;
  const int row = blockIdx.x * 4 + w;
  const int b = row / V_, v = row % V_;
  const int ev = type_[b * S_ + s];

  if (s == 0) {
    const float eb1r = eb1[lane], eW2r = eW2[lane], eb2r = eb2[0];
    if (lane < 32) xls[w][lane] = h0[v * HD_ + lane];
    float a = dotWxT<8, 64>(eW1, xls[w], eb1r, lane);
    float t = tanhf(a) * eW2r;
#pragma unroll
    for (int o = 1; o < 64; o <<= 1) t += __shfl_xor(t, o, 64);
    float l0 = fmaxf(t + eb2r, 0.0f) + log1pf(expf(-fabsf(t + eb2r)));
    if (lane == 0) {
      dout[1 + (b * S_ + 0) * V_ + v] = l0;
      acc[row] = 0.0f;
      if (v == ev) ltlog[0 * B_ + b] = logf(l0 + 1e-16f) * mask_[b * S_ + 0];
    }
  }

  const float mb1r = mb1[lane], jb1r = jb1[lane];
  const float mb2r = (lane < 32) ? mb2[lane] : 0.0f;
  const float jb2r = (lane < 32) ? jb2[lane] : 0.0f;

  if (lane < 32) {
    xls[w][lane]      = (s == 0) ? h0[ev * HD_ + lane] : hsrc[(b * V_ + ev) * HD_ + lane];
    xls[w][32 + lane] = (s == 0) ? h0[v * HD_ + lane]  : hsrc[row * HD_ + lane];
  }
  float a = dotWxT<16, 64>(mW1, xls[w], mb1r, lane);
  als[w][lane] = tanhf(a);

  float p;
  {
    int idx = ev * V_ + v;
    float l0v = logits[idx], l1v = logits[V_ * V_ + idx];
    float mx = fmaxf(l0v, l1v);
    float e0 = expf(l0v - mx), e1 = expf(l1v - mx);
    p = e1 / (e0 + e1);
  }
  float hn = 0.0f;
  if (lane < 32) {
    float mj = dotWxT<16, 32>(mW2, als[w], mb2r, lane);
    hn = xls[w][32 + lane] + mj * p;
  }
  if (v == ev) {
    if (lane < 32) xls[w][lane] = hn;
    float aj = dotWxT<8, 64>(jW1, xls[w], jb1r, lane);
    als[w][lane] = tanhf(aj);
    if (lane < 32) {
      float jj = dotWxT<16, 32>(jW2, als[w], jb2r, lane);
      hn += jj;
    }
  }
  if (lane < 32) hdst[row * HD_ + lane] = hn;
}

// ---------------- deterministic final reduce ----------------
__global__ void reduce_k(const float* __restrict__ acc, const float* __restrict__ ltlog,
                         float* __restrict__ dout) {
  __shared__ double sh[512];
  int t = threadIdx.x;
  double ia = 0.0, st = 0.0;
  for (int i = t; i < NROW; i += 256) ia += (double)acc[i];
  for (int i = t; i < B_ * S_; i += 256) st += (double)ltlog[i];
  sh[t] = ia; sh[256 + t] = st;
  __syncthreads();
  for (int o = 128; o > 0; o >>= 1) {
    if (t < o) { sh[t] += sh[t + o]; sh[256 + t] += sh[256 + t + o]; }
    __syncthreads();
  }
  if (t == 0) dout[0] = (float)(0.5 * sh[0] - sh[256]);
}

extern "C" void kernel_launch(void* const* d_in, const int* in_sizes, int n_in,
                              void* d_out, int out_size, void* d_ws, size_t ws_size,
                              hipStream_t stream) {
  const float* time_  = (const float*)d_in[0];
  const int*   type_  = (const int*)d_in[1];
  const float* mask_  = (const float*)d_in[2];
  const float* logits = (const float*)d_in[3];
  const float* h0     = (const float*)d_in[4];
  const float* fW1 = (const float*)d_in[5];  const float* fb1 = (const float*)d_in[6];
  const float* fW2 = (const float*)d_in[7];  const float* fb2 = (const float*)d_in[8];
  const float* fW3 = (const float*)d_in[9];  const float* fb3 = (const float*)d_in[10];
  const float* gW1 = (const float*)d_in[11]; const float* gb1 = (const float*)d_in[12];
  const float* gW2 = (const float*)d_in[13]; const float* gb2 = (const float*)d_in[14];
  const float* gW3 = (const float*)d_in[15]; const float* gb3 = (const float*)d_in[16];
  const float* eW1 = (const float*)d_in[17]; const float* eb1 = (const float*)d_in[18];
  const float* eW2 = (const float*)d_in[19]; const float* eb2 = (const float*)d_in[20];
  const float* jW1 = (const float*)d_in[21]; const float* jb1 = (const float*)d_in[22];
  const float* jW2 = (const float*)d_in[23]; const float* jb2 = (const float*)d_in[24];
  const float* mW1 = (const float*)d_in[25]; const float* mb1 = (const float*)d_in[26];
  const float* mW2 = (const float*)d_in[27]; const float* mb2 = (const float*)d_in[28];
  float* out = (float*)d_out;

  float* ws    = (float*)d_ws;
  float* hA    = ws + WO_HA;
  float* hB    = ws + WO_HB;
  float* acc   = ws + WO_ACC;
  float* prevl = ws + WO_PREVL;
  float* prevt = ws + WO_PREVT;
  float* ltlog = ws + WO_LTLOG;

  // host-side key chain: key(42); 310x fold-like split
  uint32_t kh = 0u, kl = 42u;
  uint32_t subs[310][2];
  for (int n = 0; n < 310; ++n) {
    uint32_t a0 = 0u, a1 = 0u; tf2x32(kh, kl, a0, a1);
    uint32_t b0 = 0u, b1 = 1u; tf2x32(kh, kl, b0, b1);
    subs[n][0] = b0; subs[n][1] = b1;
    kh = a0; kl = a1;
  }

  prep_k<<<73, 256, 0, stream>>>(fW1, gW1, fW3, gW3, eW1, fW2, gW2, ws);

  dim3 grid(NROW / 4), blk(256);
  msg_k<<<grid, blk, 0, stream>>>(type_, mask_, logits, h0,
                                  mW1, mb1, mW2, mb2, jW1, jb1, jW2, jb2,
                                  eW1, eb1, eW2, eb2,
                                  hA, hA, acc, ltlog, out, 0);
  for (int s = 1; s <= 31; ++s) {
    float* hcur = ((s - 1) & 1) ? hB : hA;
    SubK sk;
    for (int j = 0; j < ND_; ++j) {
      sk.k[j][0] = subs[(s - 1) * ND_ + j][0];
      sk.k[j][1] = subs[(s - 1) * ND_ + j][1];
    }
    euler_k<<<grid, blk, 0, stream>>>(time_, type_, mask_, ws,
                                      fb1, fb2, fb3, gb1, gb2, gb3,
                                      eb1, eW2, eb2,
                                      hcur, acc, prevl, prevt, ltlog, out, s, sk);
    if (s < 31) {
      float* hdst = (s & 1) ? hB : hA;
      msg_k<<<grid, blk, 0, stream>>>(type_, mask_, logits, h0,
                                      mW1, mb1, mW2, mb2, jW1, jb1, jW2, jb2,
                                      eW1, eb1, eW2, eb2,
                                      hcur, hdst, acc, ltlog, out, s);
    }
  }
  reduce_k<<<1, 256, 0, stream>>>(acc, ltlog, out);
}

// Round 5
// 1237.957 us; speedup vs baseline: 8.0718x; 8.0718x over previous
//
#include <hip/hip_runtime.h>
#include <hip/hip_fp16.h>
#include <stdint.h>

#define B_  32
#define S_  32
#define V_  100
#define HD_ 32
#define HID_ 64
#define ND_ 10
#define NROW (B_*V_)
#define NTILE 7
#define NBLK (B_*NTILE)   // 224 (batch,tile) blocks

// ---- workspace float offsets ----
#define WO_WB    0                              // 38 frags * 64 lanes * 8 f16 = 9728 floats
#define WO_HA    9728
#define WO_HB    (WO_HA + NROW*HD_)             // 112128
#define WO_ACC   (WO_HB + NROW*HD_)             // 214528
#define WO_PREVL (WO_ACC + NROW)
#define WO_PREVT (WO_PREVL + NROW)
#define WO_LTLOG (WO_PREVT + NROW)
#define WO_END   (WO_LTLOG + B_*S_)             // 225152 floats (16B aligned)
#define NOISE_FLOATS ((size_t)310 * NBLK * 64 * 8)

typedef __attribute__((ext_vector_type(8))) _Float16 f16x8;
typedef __attribute__((ext_vector_type(4))) float f32x4;

#define LGKM_FENCE asm volatile("s_waitcnt lgkmcnt(0)" ::: "memory")

// ---------------- threefry2x32 (JAX-compatible, verified passing) ----------------
__host__ __device__ inline void tf2x32(uint32_t k0, uint32_t k1,
                                       uint32_t& x0, uint32_t& x1) {
  uint32_t ks0 = k0, ks1 = k1, ks2 = k0 ^ k1 ^ 0x1BD11BDAu;
#define TFR(r) { x0 += x1; x1 = (x1 << (r)) | (x1 >> (32 - (r))); x1 ^= x0; }
  x0 += ks0; x1 += ks1;
  TFR(13) TFR(15) TFR(26) TFR(6)
  x0 += ks1; x1 += ks2 + 1u;
  TFR(17) TFR(29) TFR(16) TFR(24)
  x0 += ks2; x1 += ks0 + 2u;
  TFR(13) TFR(15) TFR(26) TFR(6)
  x0 += ks0; x1 += ks1 + 3u;
  TFR(17) TFR(29) TFR(16) TFR(24)
  x0 += ks1; x1 += ks2 + 4u;
  TFR(13) TFR(15) TFR(26) TFR(6)
  x0 += ks2; x1 += ks0 + 5u;
#undef TFR
}

// ---------------- erfinv (XLA / Giles f32 polynomial) — keep precise ----------------
__device__ __forceinline__ float erfinv_f(float x) {
  float w = -log1pf(-x * x);
  float p;
  if (w < 5.0f) {
    w -= 2.5f;
    p = 2.81022636e-08f;
    p = fmaf(p, w, 3.43273939e-07f);
    p = fmaf(p, w, -3.5233877e-06f);
    p = fmaf(p, w, -4.39150654e-06f);
    p = fmaf(p, w, 0.00021858087f);
    p = fmaf(p, w, -0.00125372503f);
    p = fmaf(p, w, -0.00417768164f);
    p = fmaf(p, w, 0.246640727f);
    p = fmaf(p, w, 1.50140941f);
  } else {
    w = sqrtf(w) - 3.0f;
    p = -0.000200214257f;
    p = fmaf(p, w, 0.000100950558f);
    p = fmaf(p, w, 0.00134934322f);
    p = fmaf(p, w, -0.00367342844f);
    p = fmaf(p, w, 0.00573950773f);
    p = fmaf(p, w, -0.0076224613f);
    p = fmaf(p, w, 0.00943887047f);
    p = fmaf(p, w, 1.00167406f);
    p = fmaf(p, w, 2.83297682f);
  }
  return p * x;
}

// ---------------- fast device math ----------------
__device__ __forceinline__ float tanh_e(float x) {
  // tanh(x) = 1 - 2/(e^{2x}+1); handles +-inf/sat correctly, ~1e-7 rel err
  float e = __builtin_amdgcn_exp2f(x * 2.885390082f);
  return 1.0f - 2.0f * __builtin_amdgcn_rcpf(e + 1.0f);
}
__device__ __forceinline__ float softplus_fast(float x) {
  return fmaxf(x, 0.0f) + __logf(1.0f + __expf(-fabsf(x)));
}
__device__ __forceinline__ unsigned short f16b(float x) {
  __half h = __float2half(x);           // RNE
  return *reinterpret_cast<unsigned short*>(&h);
}
__device__ __forceinline__ f32x4 MF(f16x8 a, f16x8 b, f32x4 c) {
  return __builtin_amdgcn_mfma_f32_16x16x32_f16(a, b, c, 0, 0, 0);
}

struct SubK { uint32_t k[ND_][2]; };
struct AllK { uint32_t k[310][2]; };

// noise values for one wave: v = t*4+reg -> (row = row0+4g+reg, dim = li+16t)
__device__ __forceinline__ void noise8(int row0, int lane, uint32_t k0, uint32_t k1,
                                       float* n) {
  int g = lane >> 4, li = lane & 15;
#pragma unroll
  for (int v = 0; v < 8; ++v) {
    int reg = v & 3, t = v >> 2;
    int row = row0 + 4 * g + reg;
    uint32_t x0 = 0u, x1 = (uint32_t)(row * HD_ + li + 16 * t);
    tf2x32(k0, k1, x0, x1);
    uint32_t bits = x0 ^ x1;
    float fr = __uint_as_float(0x3f800000u | (bits >> 9)) - 1.0f;
    const float LOW = -0.99999994f;
    float u = fmaxf(LOW, fr * 2.0f + LOW);
    n[v] = 1.4142135f * erfinv_f(u);
  }
}

// ---------------- prep: build 38 f16 MFMA B-fragments ----------------
// frag layout: [fid][lane][8 halves], lane holds n = n0+(lane&15), slots s = k0+8g+j.
// K-dim is PERMUTED to match the packed activation/h LDS layouts:
//   h-perm   (L1,e1): k = (s>>1) + 16*(s&1)
//   act-perm (L2,L3,e2): k = (s>>2) + 16*(s&3)
__global__ void prep_k(const float* __restrict__ fW1, const float* __restrict__ gW1,
                       const float* __restrict__ fW2, const float* __restrict__ gW2,
                       const float* __restrict__ fW3, const float* __restrict__ gW3,
                       const float* __restrict__ eW1, const float* __restrict__ eW2,
                       unsigned short* __restrict__ wb) {
  int tid = blockIdx.x * 256 + threadIdx.x;
  if (tid >= 38 * 64) return;
  int fid = tid >> 6, lane = tid & 63;
  int g = lane >> 4, li = lane & 15;
  const float* src; int k0 = 0, n0 = 0, ncol = HID_; bool hperm = false, col0 = false;
  if (fid < 4)       { src = fW1; n0 = 16 * fid;       hperm = true; }
  else if (fid < 8)  { src = gW1; n0 = 16 * (fid - 4); hperm = true; }
  else if (fid < 16) { int q = fid - 8;  src = fW2; n0 = 16 * (q >> 1); k0 = 32 * (q & 1); }
  else if (fid < 24) { int q = fid - 16; src = gW2; n0 = 16 * (q >> 1); k0 = 32 * (q & 1); }
  else if (fid < 28) { int q = fid - 24; src = fW3; n0 = 16 * (q >> 1); k0 = 32 * (q & 1); ncol = HD_; }
  else if (fid < 32) { int q = fid - 28; src = gW3; n0 = 16 * (q >> 1); k0 = 32 * (q & 1); ncol = HD_; }
  else if (fid < 36) { src = eW1; n0 = 16 * (fid - 32); hperm = true; }
  else               { src = eW2; k0 = 32 * (fid - 36); col0 = true; }
  unsigned short v[8];
#pragma unroll
  for (int j = 0; j < 8; ++j) {
    int s = k0 + 8 * g + j;
    int k = hperm ? ((s >> 1) + 16 * (s & 1)) : ((s >> 2) + 16 * (s & 3));
    float x;
    if (col0) x = (li == 0) ? src[k] : 0.0f;
    else      x = src[k * ncol + (n0 + li)];
    v[j] = f16b(x);
  }
  uint4 o;
  o.x = (uint32_t)v[0] | ((uint32_t)v[1] << 16);
  o.y = (uint32_t)v[2] | ((uint32_t)v[3] << 16);
  o.z = (uint32_t)v[4] | ((uint32_t)v[5] << 16);
  o.w = (uint32_t)v[6] | ((uint32_t)v[7] << 16);
  ((uint4*)wb)[fid * 64 + lane] = o;
}

// ---------------- noise precompute (full GPU) ----------------
__global__ void noise_k(float* __restrict__ np, AllK ak) {
  int pair = blockIdx.x * 4 + (threadIdx.x >> 6);   // (sg, bid)
  int lane = threadIdx.x & 63;
  int sg = pair / NBLK, bid = pair - sg * NBLK;
  int b = bid / NTILE, tile = bid - b * NTILE;
  int row0 = b * V_ + tile * 16;
  float n[8];
  noise8(row0, lane, ak.k[sg][0], ak.k[sg][1], n);
  float* dst = np + ((size_t)pair * 64 + lane) * 8;
  f32x4 a = {n[0], n[1], n[2], n[3]}, c = {n[4], n[5], n[6], n[7]};
  ((f32x4*)dst)[0] = a;
  ((f32x4*)dst)[1] = c;
}

// ---------------- Euler kernel: MFMA, one 16-row tile per wave ----------------
__launch_bounds__(64, 1)
__global__ void euler_k(const float* __restrict__ time_, const int* __restrict__ type_,
                        const float* __restrict__ mask_, const float* __restrict__ wsf,
                        const float* __restrict__ fb1, const float* __restrict__ fb2,
                        const float* __restrict__ fb3, const float* __restrict__ gb1,
                        const float* __restrict__ gb2, const float* __restrict__ gb3,
                        const float* __restrict__ eb1, const float* __restrict__ eb2,
                        const float* __restrict__ fW1, const float* __restrict__ gW1,
                        float* __restrict__ h, float* __restrict__ acc,
                        float* __restrict__ prevl, float* __restrict__ prevt,
                        float* __restrict__ ltlog, float* __restrict__ dout,
                        const float* __restrict__ noisep, int s, SubK sk) {
  __shared__ unsigned short actF[16 * 72];   // packed cols: c = 4*(n&15) + (n>>4)
  __shared__ unsigned short actG[16 * 72];
  __shared__ unsigned short hTl[16 * 40];    // packed cols: c = 2*(d&15) + (d>>4)
  __shared__ f16x8 wl[14 * 64];              // L1f 0-3, L1g 4-7, e1 8-11, e2 12-13

  const int lane = threadIdx.x;
  const int g = lane >> 4, li = lane & 15;
  const int bid = blockIdx.x;
  const int b = bid / NTILE, tile = bid - b * NTILE;
  const int row0 = b * V_ + tile * 16;
  const int rmax = b * V_ + (V_ - 1);

  const f16x8* WBv = (const f16x8*)wsf;
#pragma unroll
  for (int i = 0; i < 8; ++i) wl[i * 64 + lane] = WBv[i * 64 + lane];
#pragma unroll
  for (int i = 0; i < 4; ++i) wl[(8 + i) * 64 + lane] = WBv[(32 + i) * 64 + lane];
#pragma unroll
  for (int i = 0; i < 2; ++i) wl[(12 + i) * 64 + lane] = WBv[(36 + i) * 64 + lane];

  f16x8 w2f[8], w2g[8], w3f[4], w3g[4];
#pragma unroll
  for (int i = 0; i < 8; ++i) w2f[i] = WBv[(8 + i) * 64 + lane];
#pragma unroll
  for (int i = 0; i < 8; ++i) w2g[i] = WBv[(16 + i) * 64 + lane];
#pragma unroll
  for (int i = 0; i < 4; ++i) w3f[i] = WBv[(24 + i) * 64 + lane];
#pragma unroll
  for (int i = 0; i < 4; ++i) w3g[i] = WBv[(28 + i) * 64 + lane];

  float fb1v[4], gb1v[4], fb2v[4], gb2v[4], eb1v[4], fw32[4], fw33[4], gw32[4];
#pragma unroll
  for (int nt = 0; nt < 4; ++nt) {
    int n = li + 16 * nt;
    fb1v[nt] = fb1[n]; gb1v[nt] = gb1[n];
    fb2v[nt] = fb2[n]; gb2v[nt] = gb2[n];
    eb1v[nt] = eb1[n];
    fw32[nt] = fW1[32 * HID_ + n]; fw33[nt] = fW1[33 * HID_ + n];
    gw32[nt] = gW1[32 * HID_ + n];
  }
  float fb3v[2], gb3v[2];
#pragma unroll
  for (int nt = 0; nt < 2; ++nt) { fb3v[nt] = fb3[li + 16 * nt]; gb3v[nt] = gb3[li + 16 * nt]; }
  const float eb2v = eb2[0];

  const float t0 = time_[b * S_ + s - 1], t1 = time_[b * S_ + s];
  const float dt = (t1 - t0) / 10.0f;
  const float sq = sqrtf(dt);
  const float msk = mask_[b * S_ + s], mskp = mask_[b * S_ + s - 1];

  // load h (f32 state stays in registers, D-frag layout), build hT in LDS (f16)
  float hv[2][4];
#pragma unroll
  for (int t = 0; t < 2; ++t)
#pragma unroll
    for (int reg = 0; reg < 4; ++reg) {
      int rv = row0 + 4 * g + reg; if (rv > rmax) rv = rmax;
      hv[t][reg] = h[rv * HD_ + li + 16 * t];
    }
#pragma unroll
  for (int reg = 0; reg < 4; ++reg) {
    uint32_t u = (uint32_t)f16b(hv[0][reg]) | ((uint32_t)f16b(hv[1][reg]) << 16);
    *(uint32_t*)&hTl[(4 * g + reg) * 40 + 2 * li] = u;
  }
  LGKM_FENCE;

  float accv[4], lprev[4];
#pragma unroll
  for (int reg = 0; reg < 4; ++reg) {
    int rv = row0 + 4 * g + reg; if (rv > rmax) rv = rmax;
    accv[reg] = acc[rv];
  }

  auto echain = [&](float* lout) {
    f16x8 ahe = *(const f16x8*)&hTl[li * 40 + 8 * g];
    f32x4 ce[4];
#pragma unroll
    for (int nt = 0; nt < 4; ++nt) {
      f32x4 c = {eb1v[nt], eb1v[nt], eb1v[nt], eb1v[nt]};
      ce[nt] = MF(ahe, wl[(8 + nt) * 64 + lane], c);
    }
#pragma unroll
    for (int reg = 0; reg < 4; ++reg) {
      uint32_t lo = (uint32_t)f16b(tanh_e(ce[0][reg])) | ((uint32_t)f16b(tanh_e(ce[1][reg])) << 16);
      uint32_t hi = (uint32_t)f16b(tanh_e(ce[2][reg])) | ((uint32_t)f16b(tanh_e(ce[3][reg])) << 16);
      uint2 tmp; tmp.x = lo; tmp.y = hi;
      *(uint2*)&actF[(4 * g + reg) * 72 + 4 * li] = tmp;
    }
    LGKM_FENCE;
    f16x8 ae0 = *(const f16x8*)&actF[li * 72 + 8 * g];
    f16x8 ae1 = *(const f16x8*)&actF[li * 72 + 32 + 8 * g];
    f32x4 c2 = {eb2v, eb2v, eb2v, eb2v};
    c2 = MF(ae0, wl[12 * 64 + lane], c2);
    c2 = MF(ae1, wl[13 * 64 + lane], c2);
#pragma unroll
    for (int reg = 0; reg < 4; ++reg) lout[reg] = softplus_fast(c2[reg]);
  };

  echain(lprev);   // l_init of this interval
  if (s > 1) {
#pragma unroll
    for (int reg = 0; reg < 4; ++reg) {
      int rv = row0 + 4 * g + reg; if (rv > rmax) rv = rmax;
      accv[reg] += (prevl[rv] * mskp + lprev[reg] * msk) * (t0 - prevt[rv]) * msk;
    }
  }

#pragma unroll 1
  for (int j = 0; j < ND_; ++j) {
    const float dft = dt * (float)(j + 1);
    float nz[8];
    if (noisep) {
      const float* q = noisep + (((size_t)((s - 1) * ND_ + j) * NBLK + bid) * 64 + lane) * 8;
      f32x4 q0 = ((const f32x4*)q)[0], q1 = ((const f32x4*)q)[1];
      nz[0] = q0[0]; nz[1] = q0[1]; nz[2] = q0[2]; nz[3] = q0[3];
      nz[4] = q1[0]; nz[5] = q1[1]; nz[6] = q1[2]; nz[7] = q1[3];
    } else {
      noise8(row0, lane, sk.k[j][0], sk.k[j][1], nz);
    }

    f16x8 ah = *(const f16x8*)&hTl[li * 40 + 8 * g];
    // ---- L1 (f & g), K-tile0 = h via MFMA; dft/t0 columns via VALU ----
    f32x4 cf[4], cg[4];
#pragma unroll
    for (int nt = 0; nt < 4; ++nt) {
      f32x4 c = {fb1v[nt], fb1v[nt], fb1v[nt], fb1v[nt]};
      cf[nt] = MF(ah, wl[nt * 64 + lane], c);
      f32x4 d = {gb1v[nt], gb1v[nt], gb1v[nt], gb1v[nt]};
      cg[nt] = MF(ah, wl[(4 + nt) * 64 + lane], d);
    }
    float addf[4], addg[4];
#pragma unroll
    for (int nt = 0; nt < 4; ++nt) {
      addf[nt] = dft * fw32[nt] + t0 * fw33[nt];
      addg[nt] = dft * gw32[nt];
    }
#pragma unroll
    for (int reg = 0; reg < 4; ++reg) {
      uint32_t lo = (uint32_t)f16b(tanh_e(cf[0][reg] + addf[0])) | ((uint32_t)f16b(tanh_e(cf[1][reg] + addf[1])) << 16);
      uint32_t hi = (uint32_t)f16b(tanh_e(cf[2][reg] + addf[2])) | ((uint32_t)f16b(tanh_e(cf[3][reg] + addf[3])) << 16);
      uint2 t1v; t1v.x = lo; t1v.y = hi;
      *(uint2*)&actF[(4 * g + reg) * 72 + 4 * li] = t1v;
      uint32_t lo2 = (uint32_t)f16b(tanh_e(cg[0][reg] + addg[0])) | ((uint32_t)f16b(tanh_e(cg[1][reg] + addg[1])) << 16);
      uint32_t hi2 = (uint32_t)f16b(tanh_e(cg[2][reg] + addg[2])) | ((uint32_t)f16b(tanh_e(cg[3][reg] + addg[3])) << 16);
      uint2 t2v; t2v.x = lo2; t2v.y = hi2;
      *(uint2*)&actG[(4 * g + reg) * 72 + 4 * li] = t2v;
    }
    LGKM_FENCE;
    // ---- L2 ----
    f16x8 af0 = *(const f16x8*)&actF[li * 72 + 8 * g];
    f16x8 af1 = *(const f16x8*)&actF[li * 72 + 32 + 8 * g];
    f16x8 ag0 = *(const f16x8*)&actG[li * 72 + 8 * g];
    f16x8 ag1 = *(const f16x8*)&actG[li * 72 + 32 + 8 * g];
#pragma unroll
    for (int nt = 0; nt < 4; ++nt) {
      f32x4 c = {fb2v[nt], fb2v[nt], fb2v[nt], fb2v[nt]};
      c = MF(af0, w2f[2 * nt], c);
      cf[nt] = MF(af1, w2f[2 * nt + 1], c);
      f32x4 d = {gb2v[nt], gb2v[nt], gb2v[nt], gb2v[nt]};
      d = MF(ag0, w2g[2 * nt], d);
      cg[nt] = MF(ag1, w2g[2 * nt + 1], d);
    }
#pragma unroll
    for (int reg = 0; reg < 4; ++reg) {
      uint32_t lo = (uint32_t)f16b(tanh_e(cf[0][reg])) | ((uint32_t)f16b(tanh_e(cf[1][reg])) << 16);
      uint32_t hi = (uint32_t)f16b(tanh_e(cf[2][reg])) | ((uint32_t)f16b(tanh_e(cf[3][reg])) << 16);
      uint2 t1v; t1v.x = lo; t1v.y = hi;
      *(uint2*)&actF[(4 * g + reg) * 72 + 4 * li] = t1v;
      uint32_t lo2 = (uint32_t)f16b(tanh_e(cg[0][reg])) | ((uint32_t)f16b(tanh_e(cg[1][reg])) << 16);
      uint32_t hi2 = (uint32_t)f16b(tanh_e(cg[2][reg])) | ((uint32_t)f16b(tanh_e(cg[3][reg])) << 16);
      uint2 t2v; t2v.x = lo2; t2v.y = hi2;
      *(uint2*)&actG[(4 * g + reg) * 72 + 4 * li] = t2v;
    }
    LGKM_FENCE;
    // ---- L3: drift (f) and diff (g), N=32 ----
    af0 = *(const f16x8*)&actF[li * 72 + 8 * g];
    af1 = *(const f16x8*)&actF[li * 72 + 32 + 8 * g];
    ag0 = *(const f16x8*)&actG[li * 72 + 8 * g];
    ag1 = *(const f16x8*)&actG[li * 72 + 32 + 8 * g];
    f32x4 dr[2], di[2];
#pragma unroll
    for (int nt = 0; nt < 2; ++nt) {
      f32x4 c = {fb3v[nt], fb3v[nt], fb3v[nt], fb3v[nt]};
      c = MF(af0, w3f[2 * nt], c);
      dr[nt] = MF(af1, w3f[2 * nt + 1], c);
      f32x4 d = {gb3v[nt], gb3v[nt], gb3v[nt], gb3v[nt]};
      d = MF(ag0, w3g[2 * nt], d);
      di[nt] = MF(ag1, w3g[2 * nt + 1], d);
    }
    // ---- h update (f32) + refresh hT ----
#pragma unroll
    for (int t = 0; t < 2; ++t)
#pragma unroll
      for (int reg = 0; reg < 4; ++reg)
        hv[t][reg] += dr[t][reg] * dt + di[t][reg] * sq * nz[t * 4 + reg];
#pragma unroll
    for (int reg = 0; reg < 4; ++reg) {
      uint32_t u = (uint32_t)f16b(hv[0][reg]) | ((uint32_t)f16b(hv[1][reg]) << 16);
      *(uint32_t*)&hTl[(4 * g + reg) * 40 + 2 * li] = u;
    }
    LGKM_FENCE;
    // ---- intensity + trapezoid ----
    float l[4];
    echain(l);
    float tj = t0 + dt * (float)j, tj1 = t0 + dt * (float)(j + 1);
    float dtm = (tj1 - tj) * msk;
#pragma unroll
    for (int reg = 0; reg < 4; ++reg) {
      accv[reg] += (lprev[reg] * msk + l[reg] * msk) * dtm;
      lprev[reg] = l[reg];
    }
  }

  // ---- epilogue: stores (guard padded rows) ----
#pragma unroll
  for (int t = 0; t < 2; ++t)
#pragma unroll
    for (int reg = 0; reg < 4; ++reg) {
      int v = tile * 16 + 4 * g + reg;
      if (v < V_) h[(row0 + 4 * g + reg) * HD_ + li + 16 * t] = hv[t][reg];
    }
  if (li == 0) {
    int ev = type_[b * S_ + s];
    float pt = t0 + dt * 10.0f;
#pragma unroll
    for (int reg = 0; reg < 4; ++reg) {
      int v = tile * 16 + 4 * g + reg;
      if (v < V_) {
        int rv = row0 + 4 * g + reg;
        acc[rv] = accv[reg];
        prevl[rv] = lprev[reg];
        prevt[rv] = pt;
        dout[1 + (b * S_ + s) * V_ + v] = lprev[reg];
        if (v == ev) ltlog[s * B_ + b] = logf(lprev[reg] + 1e-16f) * msk;
      }
    }
  }
}

// ---------------- msg_jump kernel (unchanged from passing round 3) ----------------
template<int K4, int O>
__device__ __forceinline__ float dotWxT(const float* __restrict__ W,
                                        const float* __restrict__ x,
                                        float a, int lane) {
#pragma unroll
  for (int kb = 0; kb < K4; ++kb) {
    float4 xv = *(const float4*)(x + kb * 4);
    a = fmaf(xv.x, W[(kb * 4 + 0) * O + lane], a);
    a = fmaf(xv.y, W[(kb * 4 + 1) * O + lane], a);
    a = fmaf(xv.z, W[(kb * 4 + 2) * O + lane], a);
    a = fmaf(xv.w, W[(kb * 4 + 3) * O + lane], a);
  }
  return a;
}

__launch_bounds__(256)
__global__ void msg_k(const int* __restrict__ type_, const float* __restrict__ mask_,
                      const float* __restrict__ logits, const float* __restrict__ h0,
                      const float* __restrict__ mW1, const float* __restrict__ mb1,
                      const float* __restrict__ mW2, const float* __restrict__ mb2,
                      const float* __restrict__ jW1, const float* __restrict__ jb1,
                      const float* __restrict__ jW2, const float* __restrict__ jb2,
                      const float* __restrict__ eW1, const float* __restrict__ eb1,
                      const float* __restrict__ eW2, const float* __restrict__ eb2,
                      const float* __restrict__ hsrc, float* __restrict__ hdst,
                      float* __restrict__ acc, float* __restrict__ ltlog,
                      float* __restrict__ dout, int s) {
  __shared__ float xls[4][64];
  __shared__ float als[4][64];
  const int w = threadIdx.x >> 6, lane = threadIdx.x & 63;
  const int row = blockIdx.x * 4 + w;
  const int b = row / V_, v = row % V_;
  const int ev = type_[b * S_ + s];

  if (s == 0) {
    const float eb1r = eb1[lane], eW2r = eW2[lane], eb2r = eb2[0];
    if (lane < 32) xls[w][lane] = h0[v * HD_ + lane];
    float a = dotWxT<8, 64>(eW1, xls[w], eb1r, lane);
    float t = tanhf(a) * eW2r;
#pragma unroll
    for (int o = 1; o < 64; o <<= 1) t += __shfl_xor(t, o, 64);
    float l0 = fmaxf(t + eb2r, 0.0f) + log1pf(expf(-fabsf(t + eb2r)));
    if (lane == 0) {
      dout[1 + (b * S_ + 0) * V_ + v] = l0;
      acc[row] = 0.0f;
      if (v == ev) ltlog[0 * B_ + b] = logf(l0 + 1e-16f) * mask_[b * S_ + 0];
    }
  }

  const float mb1r = mb1[lane], jb1r = jb1[lane];
  const float mb2r = (lane < 32) ? mb2[lane] : 0.0f;
  const float jb2r = (lane < 32) ? jb2[lane] : 0.0f;

  if (lane < 32) {
    xls[w][lane]      = (s == 0) ? h0[ev * HD_ + lane] : hsrc[(b * V_ + ev) * HD_ + lane];
    xls[w][32 + lane] = (s == 0) ? h0[v * HD_ + lane]  : hsrc[row * HD_ + lane];
  }
  float a = dotWxT<16, 64>(mW1, xls[w], mb1r, lane);
  als[w][lane] = tanhf(a);

  float p;
  {
    int idx = ev * V_ + v;
    float l0v = logits[idx], l1v = logits[V_ * V_ + idx];
    float mx = fmaxf(l0v, l1v);
    float e0 = expf(l0v - mx), e1 = expf(l1v - mx);
    p = e1 / (e0 + e1);
  }
  float hn = 0.0f;
  if (lane < 32) {
    float mj = dotWxT<16, 32>(mW2, als[w], mb2r, lane);
    hn = xls[w][32 + lane] + mj * p;
  }
  if (v == ev) {
    if (lane < 32) xls[w][lane] = hn;
    float aj = dotWxT<8, 64>(jW1, xls[w], jb1r, lane);
    als[w][lane] = tanhf(aj);
    if (lane < 32) {
      float jj = dotWxT<16, 32>(jW2, als[w], jb2r, lane);
      hn += jj;
    }
  }
  if (lane < 32) hdst[row * HD_ + lane] = hn;
}

// ---------------- deterministic final reduce ----------------
__global__ void reduce_k(const float* __restrict__ acc, const float* __restrict__ ltlog,
                         float* __restrict__ dout) {
  __shared__ double sh[512];
  int t = threadIdx.x;
  double ia = 0.0, st = 0.0;
  for (int i = t; i < NROW; i += 256) ia += (double)acc[i];
  for (int i = t; i < B_ * S_; i += 256) st += (double)ltlog[i];
  sh[t] = ia; sh[256 + t] = st;
  __syncthreads();
  for (int o = 128; o > 0; o >>= 1) {
    if (t < o) { sh[t] += sh[t + o]; sh[256 + t] += sh[256 + t + o]; }
    __syncthreads();
  }
  if (t == 0) dout[0] = (float)(0.5 * sh[0] - sh[256]);
}

extern "C" void kernel_launch(void* const* d_in, const int* in_sizes, int n_in,
                              void* d_out, int out_size, void* d_ws, size_t ws_size,
                              hipStream_t stream) {
  const float* time_  = (const float*)d_in[0];
  const int*   type_  = (const int*)d_in[1];
  const float* mask_  = (const float*)d_in[2];
  const float* logits = (const float*)d_in[3];
  const float* h0     = (const float*)d_in[4];
  const float* fW1 = (const float*)d_in[5];  const float* fb1 = (const float*)d_in[6];
  const float* fW2 = (const float*)d_in[7];  const float* fb2 = (const float*)d_in[8];
  const float* fW3 = (const float*)d_in[9];  const float* fb3 = (const float*)d_in[10];
  const float* gW1 = (const float*)d_in[11]; const float* gb1 = (const float*)d_in[12];
  const float* gW2 = (const float*)d_in[13]; const float* gb2 = (const float*)d_in[14];
  const float* gW3 = (const float*)d_in[15]; const float* gb3 = (const float*)d_in[16];
  const float* eW1 = (const float*)d_in[17]; const float* eb1 = (const float*)d_in[18];
  const float* eW2 = (const float*)d_in[19]; const float* eb2 = (const float*)d_in[20];
  const float* jW1 = (const float*)d_in[21]; const float* jb1 = (const float*)d_in[22];
  const float* jW2 = (const float*)d_in[23]; const float* jb2 = (const float*)d_in[24];
  const float* mW1 = (const float*)d_in[25]; const float* mb1 = (const float*)d_in[26];
  const float* mW2 = (const float*)d_in[27]; const float* mb2 = (const float*)d_in[28];
  float* out = (float*)d_out;

  float* ws    = (float*)d_ws;
  float* hA    = ws + WO_HA;
  float* hB    = ws + WO_HB;
  float* acc   = ws + WO_ACC;
  float* prevl = ws + WO_PREVL;
  float* prevt = ws + WO_PREVT;
  float* ltlog = ws + WO_LTLOG;

  // host-side key chain: key(42); 310x fold-like split (verified bit-exact)
  uint32_t kh = 0u, kl = 42u;
  uint32_t subs[310][2];
  for (int n = 0; n < 310; ++n) {
    uint32_t a0 = 0u, a1 = 0u; tf2x32(kh, kl, a0, a1);
    uint32_t b0 = 0u, b1 = 1u; tf2x32(kh, kl, b0, b1);
    subs[n][0] = b0; subs[n][1] = b1;
    kh = a0; kl = a1;
  }

  const bool useNoise = ws_size >= ((size_t)WO_END + NOISE_FLOATS) * 4;
  float* noisep = useNoise ? (ws + WO_END) : nullptr;

  prep_k<<<10, 256, 0, stream>>>(fW1, gW1, fW2, gW2, fW3, gW3, eW1, eW2,
                                 (unsigned short*)ws);
  if (useNoise) {
    AllK ak;
    for (int n = 0; n < 310; ++n) { ak.k[n][0] = subs[n][0]; ak.k[n][1] = subs[n][1]; }
    noise_k<<<(310 * NBLK) / 4, 256, 0, stream>>>(noisep, ak);
  }

  dim3 mgrid(NROW / 4), mblk(256);
  msg_k<<<mgrid, mblk, 0, stream>>>(type_, mask_, logits, h0,
                                    mW1, mb1, mW2, mb2, jW1, jb1, jW2, jb2,
                                    eW1, eb1, eW2, eb2,
                                    hA, hA, acc, ltlog, out, 0);
  for (int s = 1; s <= 31; ++s) {
    float* hcur = ((s - 1) & 1) ? hB : hA;
    SubK sk;
    for (int j = 0; j < ND_; ++j) {
      sk.k[j][0] = subs[(s - 1) * ND_ + j][0];
      sk.k[j][1] = subs[(s - 1) * ND_ + j][1];
    }
    euler_k<<<NBLK, 64, 0, stream>>>(time_, type_, mask_, ws,
                                     fb1, fb2, fb3, gb1, gb2, gb3, eb1, eb2,
                                     fW1, gW1,
                                     hcur, acc, prevl, prevt, ltlog, out,
                                     noisep, s, sk);
    if (s < 31) {
      float* hdst = (s & 1) ? hB : hA;
      msg_k<<<mgrid, mblk, 0, stream>>>(type_, mask_, logits, h0,
                                        mW1, mb1, mW2, mb2, jW1, jb1, jW2, jb2,
                                        eW1, eb1, eW2, eb2,
                                        hcur, hdst, acc, ltlog, out, s);
    }
  }
  reduce_k<<<1, 256, 0, stream>>>(acc, ltlog, out);
}